// Round 4
// baseline (2336.632 us; speedup 1.0000x reference)
//
#include <hip/hip_runtime.h>

typedef unsigned short u16;
typedef unsigned int u32;
typedef __attribute__((ext_vector_type(8))) short short8;
typedef __attribute__((ext_vector_type(4))) float f32x4;

constexpr int CB = 64, CT = 512, CX = 8, CH = 128;

__device__ __forceinline__ u16 f2b(float f) {
  u32 u = __float_as_uint(f);
  return (u16)((u + 0x7FFFu + ((u >> 16) & 1u)) >> 16);  // RNE bf16
}
__device__ __forceinline__ float sigf(float x) {
  return __fdividef(1.0f, 1.0f + __expf(-x));
}
__device__ __forceinline__ float tanhfast(float x) {
  return 1.0f - __fdividef(2.0f, __expf(2.0f * x) + 1.0f);
}
__device__ __forceinline__ f32x4 mfma16(short8 a, short8 b, f32x4 c) {
  return __builtin_amdgcn_mfma_f32_16x16x32_bf16(a, b, c, 0, 0, 0);
}

// LDS-only barrier: publishes LDS writes across the workgroup WITHOUT the
// vmcnt(0) drain __syncthreads() emits. Global loads/stores issued before
// this barrier stay in flight across it (consumed later via register deps /
// counted vmcnt). "memory" clobbers pin memory-op ordering around it.
__device__ __forceinline__ void barrier_lgkm() {
  asm volatile("s_waitcnt lgkmcnt(0)" ::: "memory");
  __builtin_amdgcn_s_barrier();
  asm volatile("" ::: "memory");
}

// Counted-vmcnt barrier (T4 pattern). Every loop iteration issues >=14
// vector-mem ops before this barrier: 4 h/c gathers + 2 wican + 4 swf
// fragment loads + 4 exec-masked hs/cs stores (every wave contains qd==0
// and qd==2 lanes, so all 4 store instructions always issue). vmcnt(14)
// therefore guarantees everything OLDER than the 14 newest outstanding ops
// is complete -- in particular ALL of iteration t-1's ops including its
// hs/cs stores. Iteration t+1's global gathers only touch rows <= t-2
// (2-deep LDS ping-pong covers rows t-1, t), so this is exactly the
// visibility needed, while iteration t's own stores and prefetch loads stay
// in flight across the barrier. Extra compiler-emitted vmem ops (spills)
// only add ops NEWER than t-1's stores, keeping the invariant safe.
__device__ __forceinline__ void barrier_vm14() {
  asm volatile("s_waitcnt vmcnt(14) lgkmcnt(0)" ::: "memory");
  __builtin_amdgcn_s_barrier();
  asm volatile("" ::: "memory");
}

// ---------------- ws layout (bytes) ----------------
// 0         : WgwT  bf16 [384][256]  B^T of [w_hh_w; w_ih_w]   (196608 B)
// 196608    : WahcT bf16 [512][128]  B^T of [a_hh | w_hh_c]    (131072 B)
// 327680    : WcaT  bf16 [512][128]  B^T of [w_ih_c | a_ih]    (131072 B)
// 458752    : wica  f32  [B*T][512]  [wi_c_all | a_wi_all]     (67108864 B)
// 67567616  : swb16 bf16 [B][T][X][128] skip_words pre-cast    (67108864 B)
// total ~134.7 MB

__global__ void prep_kernel(const float* __restrict__ w_ih_c, const float* __restrict__ w_hh_c,
                            const float* __restrict__ a_ih, const float* __restrict__ a_hh,
                            const float* __restrict__ w_ih_w, const float* __restrict__ w_hh_w,
                            u16* __restrict__ WgwT, u16* __restrict__ WahcT, u16* __restrict__ WcaT) {
  int gid = blockIdx.x * blockDim.x + threadIdx.x;  // 224*1024 = 229376
  if (gid < 98304) {                 // WgwT[n][k], n<384, k<256
    int n = gid >> 8, k = gid & 255;
    float v = (k < 128) ? w_hh_w[k * 384 + n] : w_ih_w[(k - 128) * 384 + n];
    WgwT[gid] = f2b(v);
  } else if (gid < 163840) {         // WahcT[n][k], n<512, k<128
    int i = gid - 98304; int n = i >> 7, k = i & 127;
    float v = (n < 128) ? a_hh[k * 128 + n] : w_hh_c[k * 384 + (n - 128)];
    WahcT[i] = f2b(v);
  } else if (gid < 229376) {         // WcaT[n][k], n<512, k<128
    int i = gid - 163840; int n = i >> 7, k = i & 127;
    float v = (n < 384) ? w_ih_c[k * 384 + n] : a_ih[k * 128 + (n - 384)];
    WcaT[i] = f2b(v);
  }
}

// skip_words f32 -> bf16, 8 elems/thread. 4096 blocks x 1024 threads x 8 = 33554432.
__global__ void prep_sw_kernel(const float* __restrict__ sw, u16* __restrict__ swb16) {
  size_t i = ((size_t)blockIdx.x * 1024 + threadIdx.x) * 8;
  float4 x0 = *(const float4*)(sw + i);
  float4 x1 = *(const float4*)(sw + i + 4);
  short8 o;
  o[0] = (short)f2b(x0.x); o[1] = (short)f2b(x0.y); o[2] = (short)f2b(x0.z); o[3] = (short)f2b(x0.w);
  o[4] = (short)f2b(x1.x); o[5] = (short)f2b(x1.y); o[6] = (short)f2b(x1.z); o[7] = (short)f2b(x1.w);
  *(short8*)(swb16 + i) = o;
}

// wica[m][n] = sum_k inp[m][k]*Wca[k][n] + bias, m = b*T+t, N=512, K=128
__global__ __launch_bounds__(256) void proj_kernel(const float* __restrict__ inp,
    const u16* __restrict__ WcaT, const float* __restrict__ bias_c,
    const float* __restrict__ a_bias, float* __restrict__ wica) {
  const int m0 = blockIdx.x * 64;
  const int wv = threadIdx.x >> 6, ln = threadIdx.x & 63;
  const int l16 = ln & 15, qd = ln >> 4;
  const int arow = m0 + wv * 16 + l16;
  short8 af[4];
#pragma unroll
  for (int kt = 0; kt < 4; ++kt) {
    const float* p = inp + (size_t)arow * 128 + kt * 32 + qd * 8;
    float4 x0 = *(const float4*)p;
    float4 x1 = *(const float4*)(p + 4);
    short8 a;
    a[0] = (short)f2b(x0.x); a[1] = (short)f2b(x0.y); a[2] = (short)f2b(x0.z); a[3] = (short)f2b(x0.w);
    a[4] = (short)f2b(x1.x); a[5] = (short)f2b(x1.y); a[6] = (short)f2b(x1.z); a[7] = (short)f2b(x1.w);
    af[kt] = a;
  }
  for (int nt = 0; nt < 32; ++nt) {
    const int col = nt * 16 + l16;
    f32x4 acc = {0.f, 0.f, 0.f, 0.f};
#pragma unroll
    for (int kt = 0; kt < 4; ++kt) {
      short8 bf = *(const short8*)(WcaT + (size_t)col * 128 + kt * 32 + qd * 8);
      acc = mfma16(af[kt], bf, acc);
    }
    const float bias = (col < 384) ? bias_c[col] : a_bias[col - 384];
#pragma unroll
    for (int r = 0; r < 4; ++r) {
      const int orow = m0 + wv * 16 + qd * 4 + r;
      wica[(size_t)orow * 512 + col] = acc[r] + bias;
    }
  }
}

// Batch-paired scan: block handles batches bA = 2*bid, bB = bA+1.
// A-matrix rows 0..7 = batch-A slots, 8..15 = batch-B slots; weights (MFMA
// B-operand) are shared, so every MFMA chain serves both batches. Final
// per-h outputs: batch A on qd==0 lanes, batch B on qd==2 lanes.
__global__ __launch_bounds__(512, 2) void scan_kernel(
    const u16* __restrict__ swb16,         // [B][T][X][128] bf16
    const int* __restrict__ srcp,          // [B][T][X]
    const int* __restrict__ cntp,          // [B][T]
    const float* __restrict__ bias_w,      // [384]
    const u16* __restrict__ WgwT,          // [384][256]
    const u16* __restrict__ WahcT,         // [512][128]
    const float* __restrict__ wica,        // [B*T][512]
    float* __restrict__ out)               // hs [B][T][128] ; cs follows
{
  const int bA = blockIdx.x * 2, bB = bA + 1;
  const int tid = threadIdx.x;
  const int wv = tid >> 6;
  const int ln = tid & 63;
  const int l16 = ln & 15;
  const int qd = ln >> 4;
  const int h = wv * 16 + l16;

  float* hsA = out + (size_t)bA * CT * CH;
  float* csA = out + (size_t)(CB + bA) * CT * CH;
  float* hsB = out + (size_t)bB * CT * CH;
  float* csB = out + (size_t)(CB + bB) * CT * CH;
  const int* srcbA = srcp + bA * CT * CX;
  const int* srcbB = srcp + bB * CT * CX;
  const int* cntbA = cntp + bA * CT;
  const int* cntbB = cntp + bB * CT;
  const float* wicabA = wica + (size_t)bA * CT * 512;
  const float* wicabB = wica + (size_t)bB * CT * 512;

  // LDS (stride 136 u16 = 272 B breaks power-of-2 bank aliasing)
  __shared__ __align__(16) u16 Asg[16 * 136];    // rows 0..7 A-slot h_x; 8..15 B-slot h_x
  __shared__ __align__(16) u16 Psg[16 * 136];    // rows 0..7 A c1_skip; 8..15 B c1_skip
  __shared__ __align__(16) u16 Hsg[16 * 136];    // row 0 h0_A; row 1 h0_B; rest zero
  __shared__ __align__(16) float Csg[16 * 128];  // c_x: rows 0..7 A, 8..15 B (fp32)
  __shared__ __align__(16) u16 hbuf[2][2][128];  // [batch][parity] bf16 h ping-pong
  __shared__ __align__(16) float cbuf[2][2][128];// [batch][parity] fp32 c ping-pong
  __shared__ float gca[2][512];                  // per batch: [0,384) wi_c ; [384,512) a_wi

  for (int i = tid; i < 16 * 136; i += 512) { Asg[i] = 0; Psg[i] = 0; Hsg[i] = 0; }
  if (tid < 128) {
    hbuf[0][0][tid] = 0; hbuf[0][1][tid] = 0; hbuf[1][0][tid] = 0; hbuf[1][1][tid] = 0;
    cbuf[0][0][tid] = 0.0f; cbuf[0][1][tid] = 0.0f; cbuf[1][0][tid] = 0.0f; cbuf[1][1][tid] = 0.0f;
  }

  // persistent B-fragments (bf16), shared by both batches -------------------
  short8 wgwf[3][8];  // gate g in {f,i,g}: col = g*128 + h; kt 0..3 h-part, 4..7 sw-part
#pragma unroll
  for (int g = 0; g < 3; ++g) {
    const int n = g * 128 + h;
#pragma unroll
    for (int kt = 0; kt < 8; ++kt)
      wgwf[g][kt] = *(const short8*)(WgwT + (size_t)n * 256 + kt * 32 + qd * 8);
  }
  short8 wacf[4][4];  // j=0: a_hh col h ; j=1..3: w_hh_c gate cols (j-1)*128+h
#pragma unroll
  for (int j = 0; j < 4; ++j) {
    const int n = j * 128 + h;
#pragma unroll
    for (int kt = 0; kt < 4; ++kt)
      wacf[j][kt] = *(const short8*)(WahcT + (size_t)n * 128 + kt * 32 + qd * 8);
  }
  const float bw0 = bias_w[h], bw1 = bias_w[128 + h], bw2 = bias_w[256 + h];

  // sw A-fragments straight from global in fragment layout: lane (l16,qd)
  // holds sw[batch = bA + (l16>>3)][slot = l16&7][kt*32 + qd*8 ..+7].
  const u16* swfbase = swb16 + ((size_t)(bA + (l16 >> 3)) * CT * CX + (l16 & 7)) * CH + qd * 8;
  short8 swf[4];
#pragma unroll
  for (int kt = 0; kt < 4; ++kt)
    swf[kt] = *(const short8*)(swfbase + kt * 32);  // t = 0

  // pipeline preload for t=0 (src/cnt also for t=1) -------------------------
  int src_cA = srcbA[wv], src_cB = srcbB[wv];
  int cnt_cA = cntbA[0],  cnt_cB = cntbB[0];
  int src_nA = srcbA[CX + wv], src_nB = srcbB[CX + wv];
  int cnt_nA = cntbA[1],  cnt_nB = cntbB[1];
  float2 h2cA = *(const float2*)(hsA + (size_t)src_cA * CH + 2 * ln);  // poison at t=0, masked (cnt=0)
  float2 c2cA = *(const float2*)(csA + (size_t)src_cA * CH + 2 * ln);
  float2 h2cB = *(const float2*)(hsB + (size_t)src_cB * CH + 2 * ln);
  float2 c2cB = *(const float2*)(csB + (size_t)src_cB * CH + 2 * ln);
  float wicacA = wicabA[tid], wicacB = wicabB[tid];
  float2 h2nA = {0.f, 0.f}, c2nA = {0.f, 0.f}, h2nB = {0.f, 0.f}, c2nB = {0.f, 0.f};
  float wicanA = 0.f, wicanB = 0.f;
  int src_n2A = 0, src_n2B = 0, cnt_n2A = 0, cnt_n2B = 0;
  __syncthreads();  // LDS init visible (full sync once; drains preloads too)

  for (int t = 0; t < CT; ++t) {
    const int par = t & 1;        // parity holding h_{t-2}; epilogue writes h_t here
    const int parp = par ^ 1;     // parity holding h_{t-1}

    // ---- stage 1: stage A rows (both batches), c_x, h0, wi parts ---------
    // src <= t-1. Rows t-1 / t-2 resolve from LDS ping-pong, so global
    // gathers only ever touch rows <= t-2 (stores get 2 barriers to land).
    if (src_cA == t - 1) {
      *(u32*)&Asg[wv * 136 + 2 * ln] = *(const u32*)&hbuf[0][parp][2 * ln];
      *(float2*)&Csg[wv * 128 + 2 * ln] = *(const float2*)&cbuf[0][parp][2 * ln];
    } else if (src_cA == t - 2) {
      *(u32*)&Asg[wv * 136 + 2 * ln] = *(const u32*)&hbuf[0][par][2 * ln];
      *(float2*)&Csg[wv * 128 + 2 * ln] = *(const float2*)&cbuf[0][par][2 * ln];
    } else {
      *(u32*)&Asg[wv * 136 + 2 * ln] = (u32)f2b(h2cA.x) | ((u32)f2b(h2cA.y) << 16);
      *(float2*)&Csg[wv * 128 + 2 * ln] = c2cA;
    }
    if (src_cB == t - 1) {
      *(u32*)&Asg[(8 + wv) * 136 + 2 * ln] = *(const u32*)&hbuf[1][parp][2 * ln];
      *(float2*)&Csg[(8 + wv) * 128 + 2 * ln] = *(const float2*)&cbuf[1][parp][2 * ln];
    } else if (src_cB == t - 2) {
      *(u32*)&Asg[(8 + wv) * 136 + 2 * ln] = *(const u32*)&hbuf[1][par][2 * ln];
      *(float2*)&Csg[(8 + wv) * 128 + 2 * ln] = *(const float2*)&cbuf[1][par][2 * ln];
    } else {
      *(u32*)&Asg[(8 + wv) * 136 + 2 * ln] = (u32)f2b(h2cB.x) | ((u32)f2b(h2cB.y) << 16);
      *(float2*)&Csg[(8 + wv) * 128 + 2 * ln] = c2cB;
    }
    gca[0][tid] = wicacA;
    gca[1][tid] = wicacB;
    if (wv == 6)  // Hsg row 0 = h0_A (= h_{t-1} of A)
      *(u32*)&Hsg[0 * 136 + 2 * ln] = *(const u32*)&hbuf[0][parp][2 * ln];
    if (wv == 7)  // Hsg row 1 = h0_B
      *(u32*)&Hsg[1 * 136 + 2 * ln] = *(const u32*)&hbuf[1][parp][2 * ln];
    barrier_lgkm();  // barrier A (LDS-only: nothing global crosses here)

    // ---- stage 2: prefetch for t+1 (in flight through barrier C) ---------
    // All loads unconditional (clamped) -> fixed vmem-op floor per iter for
    // the counted vmcnt at barrier C. Racy gathers (src_n in {t-1,t}) are
    // discarded at consumption (LDS-history path); the load is harmless.
    const int tn = (t + 1 < CT) ? (t + 1) : t;
    {
      const int tn2 = (t + 2 < CT) ? (t + 2) : (CT - 1);
      h2nA = *(const float2*)(hsA + (size_t)src_nA * CH + 2 * ln);
      c2nA = *(const float2*)(csA + (size_t)src_nA * CH + 2 * ln);
      h2nB = *(const float2*)(hsB + (size_t)src_nB * CH + 2 * ln);
      c2nB = *(const float2*)(csB + (size_t)src_nB * CH + 2 * ln);
      wicanA = wicabA[(size_t)tn * 512 + tid];
      wicanB = wicabB[(size_t)tn * 512 + tid];
      src_n2A = srcbA[tn2 * CX + wv]; src_n2B = srcbB[tn2 * CX + wv];
      cnt_n2A = cntbA[tn2];           cnt_n2B = cntbB[tn2];
    }

    // ---- stage 3: gw (both batches) + gc chains --------------------------
    // d*: 16 A-rows = both batches' slots. e*: Hsg rows 0/1 = h0_A/h0_B ->
    // output rows 0/1 = gc_A/gc_B (rows 2..15 from zero rows, discarded).
    f32x4 d0 = {0.f, 0.f, 0.f, 0.f}, d1 = d0, d2 = d0;
    f32x4 e1 = d0, e2 = d0, e3 = d0;
#pragma unroll
    for (int kt = 0; kt < 4; ++kt) {
      short8 a = *(const short8*)&Asg[l16 * 136 + kt * 32 + qd * 8];
      d0 = mfma16(a, wgwf[0][kt], d0);
      d1 = mfma16(a, wgwf[1][kt], d1);
      d2 = mfma16(a, wgwf[2][kt], d2);
      short8 hf = *(const short8*)&Hsg[l16 * 136 + kt * 32 + qd * 8];
      e1 = mfma16(hf, wacf[1][kt], e1);
      e2 = mfma16(hf, wacf[2][kt], e2);
      e3 = mfma16(hf, wacf[3][kt], e3);
    }
    {
      const u16* swfn = swfbase + (size_t)tn * (CX * CH);
#pragma unroll
      for (int kt = 0; kt < 4; ++kt) {
        d0 = mfma16(swf[kt], wgwf[0][4 + kt], d0);
        d1 = mfma16(swf[kt], wgwf[1][4 + kt], d1);
        d2 = mfma16(swf[kt], wgwf[2][4 + kt], d2);
        swf[kt] = *(const short8*)(swfn + kt * 32);  // reload for t+1 after last use
      }
    }
    // gc_A = D row 0 (qd0, reg 0); gc_B = D row 1 (qd0, reg 1). Batch A is
    // finalized on qd==0 lanes (local), batch B on qd==2 lanes (shfl from
    // lane l16). qd 1/3 lanes compute garbage gates, never used.
    const float giB = __shfl(e1[1], l16, 64);
    const float goB = __shfl(e2[1], l16, 64);
    const float ggB = __shfl(e3[1], l16, 64);
    const float gi = (qd < 2) ? e1[0] : giB;
    const float go = (qd < 2) ? e2[0] : goB;
    const float gg = (qd < 2) ? e3[0] : ggB;
    const float* gsel = (qd < 2) ? gca[0] : gca[1];
    const float awi = gsel[384 + h];
    const float i_g = sigf(gi + gsel[h]);
    const float o_g = sigf(go + gsel[128 + h]);
    const float g_g = tanhfast(gg + gsel[256 + h]);

    // c1_skip: all 16 rows real now (A rows 0..7, B rows 8..15)
    float c1s[4];
#pragma unroll
    for (int r = 0; r < 4; ++r) {
      const int row = qd * 4 + r;
      const float cx = Csg[row * 128 + h];
      const float fg = sigf(d0[r] + bw0);
      const float ig = sigf(d1[r] + bw1);
      const float gg2 = tanhfast(d2[r] + bw2);
      const float v = fg * cx + ig * gg2;
      c1s[r] = v;
      Psg[row * 136 + h] = f2b(v);
    }
    barrier_lgkm();  // barrier B (LDS-only: prefetch loads stay in flight)

    // ---- stage 5: alpha = c1_skip @ a_hh (both batches), softmax ---------
    f32x4 e0 = {0.f, 0.f, 0.f, 0.f};
#pragma unroll
    for (int kt = 0; kt < 4; ++kt) {
      short8 a = *(const short8*)&Psg[l16 * 136 + kt * 32 + qd * 8];
      e0 = mfma16(a, wacf[0][kt], e0);
    }
    float pe = 0.0f, pec = 0.0f;
    const int cntx = (qd < 2) ? cnt_cA : cnt_cB;
#pragma unroll
    for (int r = 0; r < 4; ++r) {
      const int slot = (qd * 4 + r) & 7;  // rows 0..7 A slots, 8..15 B slots
      if (slot < cntx) {                  // slots >= cnt masked (exp -> 0)
        const float al = sigf(e0[r] + awi);
        const float e = __expf(al);
        pe += e;
        pec += e * c1s[r];
      }
    }
    // Per-batch reduce: qd0<->qd1 (A rows 0..7), qd2<->qd3 (B rows 0..7).
    // NO xor-32 (that would mix batches).
    pe += __shfl_xor(pe, 16, 64);  pec += __shfl_xor(pec, 16, 64);
    const float ei = __expf(i_g);
    const float c1 = __fdividef(ei * g_g + pec, ei + pe);
    const float h1 = o_g * tanhfast(c1);

    // ---- stage 6: epilogue (A on qd0 lanes, B on qd2 lanes) --------------
    if (qd == 0) {
      hsA[(size_t)t * CH + h] = h1;
      csA[(size_t)t * CH + h] = c1;
      hbuf[0][par][h] = f2b(h1);
      cbuf[0][par][h] = c1;
    } else if (qd == 2) {
      hsB[(size_t)t * CH + h] = h1;
      csB[(size_t)t * CH + h] = c1;
      hbuf[1][par][h] = f2b(h1);
      cbuf[1][par][h] = c1;
    }
    barrier_vm14();  // barrier C: counted vmcnt — iter t-1 stores L2-visible
                     // (next-iter global gathers touch rows <= t-1 only);
                     // own stores + prefetches stay in flight.

    // rotate pipeline
    h2cA = h2nA; c2cA = c2nA; h2cB = h2nB; c2cB = c2nB;
    wicacA = wicanA; wicacB = wicanB;
    src_cA = src_nA; src_cB = src_nB; cnt_cA = cnt_nA; cnt_cB = cnt_nB;
    src_nA = src_n2A; src_nB = src_n2B; cnt_nA = cnt_n2A; cnt_nB = cnt_n2B;
  }
}

extern "C" void kernel_launch(void* const* d_in, const int* in_sizes, int n_in,
                              void* d_out, int out_size, void* d_ws, size_t ws_size,
                              hipStream_t stream) {
  (void)in_sizes; (void)n_in; (void)out_size; (void)ws_size;
  const float* inp    = (const float*)d_in[0];
  const float* skw    = (const float*)d_in[1];
  const int*   ssrc   = (const int*)d_in[3];
  const int*   scnt   = (const int*)d_in[4];
  const float* w_ih_c = (const float*)d_in[5];
  const float* w_hh_c = (const float*)d_in[6];
  const float* bias_c = (const float*)d_in[7];
  const float* a_ih   = (const float*)d_in[8];
  const float* a_hh   = (const float*)d_in[9];
  const float* a_bias = (const float*)d_in[10];
  const float* w_ih_w = (const float*)d_in[11];
  const float* w_hh_w = (const float*)d_in[12];
  const float* bias_w = (const float*)d_in[13];

  char* ws = (char*)d_ws;
  u16*   WgwT  = (u16*)(ws);
  u16*   WahcT = (u16*)(ws + 196608);
  u16*   WcaT  = (u16*)(ws + 327680);
  float* wica  = (float*)(ws + 458752);
  u16*   swb16 = (u16*)(ws + 458752 + 67108864);
  float* out   = (float*)d_out;

  prep_kernel<<<224, 1024, 0, stream>>>(w_ih_c, w_hh_c, a_ih, a_hh, w_ih_w, w_hh_w,
                                        WgwT, WahcT, WcaT);
  prep_sw_kernel<<<4096, 1024, 0, stream>>>(skw, swb16);
  proj_kernel<<<512, 256, 0, stream>>>(inp, WcaT, bias_c, a_bias, wica);
  scan_kernel<<<32, 512, 0, stream>>>(swb16, ssrc, scnt, bias_w, WgwT, WahcT, wica, out);
}

// Round 5
// 1784.983 us; speedup vs baseline: 1.3091x; 1.3091x over previous
//
#include <hip/hip_runtime.h>

typedef unsigned short u16;
typedef unsigned int u32;
typedef __attribute__((ext_vector_type(8))) short short8;
typedef __attribute__((ext_vector_type(4))) float f32x4;

constexpr int CB = 64, CT = 512, CX = 8, CH = 128;

__device__ __forceinline__ u16 f2b(float f) {
  u32 u = __float_as_uint(f);
  return (u16)((u + 0x7FFFu + ((u >> 16) & 1u)) >> 16);  // RNE bf16
}
__device__ __forceinline__ float sigf(float x) {
  return __fdividef(1.0f, 1.0f + __expf(-x));
}
__device__ __forceinline__ float tanhfast(float x) {
  return 1.0f - __fdividef(2.0f, __expf(2.0f * x) + 1.0f);
}
__device__ __forceinline__ f32x4 mfma16(short8 a, short8 b, f32x4 c) {
  return __builtin_amdgcn_mfma_f32_16x16x32_bf16(a, b, c, 0, 0, 0);
}

// LDS-only barrier: publishes LDS writes across the workgroup WITHOUT the
// vmcnt(0) drain __syncthreads() emits. Global loads/stores issued before
// this barrier stay in flight across it (consumed later via register deps /
// counted vmcnt). "memory" clobbers pin memory-op ordering around it.
__device__ __forceinline__ void barrier_lgkm() {
  asm volatile("s_waitcnt lgkmcnt(0)" ::: "memory");
  __builtin_amdgcn_s_barrier();
  asm volatile("" ::: "memory");
}

// Counted-vmcnt barrier (T4 pattern). Every loop iteration issues >=9
// vector-mem ops before this barrier (h2n, c2n, wican, swf x4, 2 stores --
// conservatively NOT counting src/cnt loads, which may become scalar SMEM
// loads). vmcnt(8) therefore guarantees everything OLDER than the 8 newest
// outstanding vmem ops is complete -- in particular ALL of iteration t-1's
// ops including its hs/cs stores. Iteration t+1's global gathers only touch
// rows <= t-2 (2-deep LDS history covers t-1, t-2), so this is exactly the
// visibility needed, while iteration t's own stores and swf/gather
// prefetches stay in flight across the barrier. Extra compiler-emitted vmem
// ops (spills) only add ops NEWER than t-1's stores -> invariant stays safe.
// [R4 HW run validated this machinery: passed, absmax 0.0117]
__device__ __forceinline__ void barrier_vm8() {
  asm volatile("s_waitcnt vmcnt(8) lgkmcnt(0)" ::: "memory");
  __builtin_amdgcn_s_barrier();
  asm volatile("" ::: "memory");
}

// ---------------- ws layout (bytes) ----------------
// 0         : WgwT  bf16 [384][256]  B^T of [w_hh_w; w_ih_w]   (196608 B)
// 196608    : WahcT bf16 [512][128]  B^T of [a_hh | w_hh_c]    (131072 B)
// 327680    : WcaT  bf16 [512][128]  B^T of [w_ih_c | a_ih]    (131072 B)
// 458752    : wica  f32  [B*T][512]  [wi_c_all | a_wi_all]     (67108864 B)
// 67567616  : swb16 bf16 [B][T][X][128] skip_words pre-cast    (67108864 B)
// total ~134.7 MB

__global__ void prep_kernel(const float* __restrict__ w_ih_c, const float* __restrict__ w_hh_c,
                            const float* __restrict__ a_ih, const float* __restrict__ a_hh,
                            const float* __restrict__ w_ih_w, const float* __restrict__ w_hh_w,
                            u16* __restrict__ WgwT, u16* __restrict__ WahcT, u16* __restrict__ WcaT) {
  int gid = blockIdx.x * blockDim.x + threadIdx.x;  // 224*1024 = 229376
  if (gid < 98304) {                 // WgwT[n][k], n<384, k<256
    int n = gid >> 8, k = gid & 255;
    float v = (k < 128) ? w_hh_w[k * 384 + n] : w_ih_w[(k - 128) * 384 + n];
    WgwT[gid] = f2b(v);
  } else if (gid < 163840) {         // WahcT[n][k], n<512, k<128
    int i = gid - 98304; int n = i >> 7, k = i & 127;
    float v = (n < 128) ? a_hh[k * 128 + n] : w_hh_c[k * 384 + (n - 128)];
    WahcT[i] = f2b(v);
  } else if (gid < 229376) {         // WcaT[n][k], n<512, k<128
    int i = gid - 163840; int n = i >> 7, k = i & 127;
    float v = (n < 384) ? w_ih_c[k * 384 + n] : a_ih[k * 128 + (n - 384)];
    WcaT[i] = f2b(v);
  }
}

// skip_words f32 -> bf16, 8 elems/thread. 4096 blocks x 1024 threads x 8 = 33554432.
__global__ void prep_sw_kernel(const float* __restrict__ sw, u16* __restrict__ swb16) {
  size_t i = ((size_t)blockIdx.x * 1024 + threadIdx.x) * 8;
  float4 x0 = *(const float4*)(sw + i);
  float4 x1 = *(const float4*)(sw + i + 4);
  short8 o;
  o[0] = (short)f2b(x0.x); o[1] = (short)f2b(x0.y); o[2] = (short)f2b(x0.z); o[3] = (short)f2b(x0.w);
  o[4] = (short)f2b(x1.x); o[5] = (short)f2b(x1.y); o[6] = (short)f2b(x1.z); o[7] = (short)f2b(x1.w);
  *(short8*)(swb16 + i) = o;
}

// wica[m][n] = sum_k inp[m][k]*Wca[k][n] + bias, m = b*T+t, N=512, K=128
__global__ __launch_bounds__(256) void proj_kernel(const float* __restrict__ inp,
    const u16* __restrict__ WcaT, const float* __restrict__ bias_c,
    const float* __restrict__ a_bias, float* __restrict__ wica) {
  const int m0 = blockIdx.x * 64;
  const int wv = threadIdx.x >> 6, ln = threadIdx.x & 63;
  const int l16 = ln & 15, qd = ln >> 4;
  const int arow = m0 + wv * 16 + l16;
  short8 af[4];
#pragma unroll
  for (int kt = 0; kt < 4; ++kt) {
    const float* p = inp + (size_t)arow * 128 + kt * 32 + qd * 8;
    float4 x0 = *(const float4*)p;
    float4 x1 = *(const float4*)(p + 4);
    short8 a;
    a[0] = (short)f2b(x0.x); a[1] = (short)f2b(x0.y); a[2] = (short)f2b(x0.z); a[3] = (short)f2b(x0.w);
    a[4] = (short)f2b(x1.x); a[5] = (short)f2b(x1.y); a[6] = (short)f2b(x1.z); a[7] = (short)f2b(x1.w);
    af[kt] = a;
  }
  for (int nt = 0; nt < 32; ++nt) {
    const int col = nt * 16 + l16;
    f32x4 acc = {0.f, 0.f, 0.f, 0.f};
#pragma unroll
    for (int kt = 0; kt < 4; ++kt) {
      short8 bf = *(const short8*)(WcaT + (size_t)col * 128 + kt * 32 + qd * 8);
      acc = mfma16(af[kt], bf, acc);
    }
    const float bias = (col < 384) ? bias_c[col] : a_bias[col - 384];
#pragma unroll
    for (int r = 0; r < 4; ++r) {
      const int orow = m0 + wv * 16 + qd * 4 + r;
      wica[(size_t)orow * 512 + col] = acc[r] + bias;
    }
  }
}

// Single-batch scan (R4 post-mortem: scan is critical-path-bound, grid 64
// on 256 CUs -> idle CUs are free; minimize per-step serial chain only).
__global__ __launch_bounds__(512, 2) void scan_kernel(
    const u16* __restrict__ swb16,         // [B][T][X][128] bf16
    const int* __restrict__ srcp,          // [B][T][X]
    const int* __restrict__ cntp,          // [B][T]
    const float* __restrict__ bias_w,      // [384]
    const u16* __restrict__ WgwT,          // [384][256]
    const u16* __restrict__ WahcT,         // [512][128]
    const float* __restrict__ wica,        // [B*T][512]
    float* __restrict__ out)               // hs [B][T][128] ; cs follows
{
  const int b = blockIdx.x;
  const int tid = threadIdx.x;
  const int wv = tid >> 6;
  const int ln = tid & 63;
  const int l16 = ln & 15;
  const int qd = ln >> 4;
  const int h = wv * 16 + l16;

  float* hs = out + (size_t)b * CT * CH;
  float* cs = out + (size_t)(CB + b) * CT * CH;
  const u16* swb = swb16 + (size_t)b * CT * CX * CH;
  const int* srcb = srcp + b * CT * CX;
  const int* cntb = cntp + b * CT;
  const float* wicab = wica + (size_t)b * CT * 512;

  // LDS (padded stride 136 u16 = 272 B breaks power-of-2 bank aliasing)
  __shared__ __align__(16) u16 Asg[16 * 136];   // rows 0..7: h_x; row 8: h0; 9..15 zero
  __shared__ __align__(16) u16 Psg[16 * 136];   // rows 0..7: c1_skip; rows 8..15 zero (masked)
  __shared__ __align__(16) float Csg[8 * 128];  // gathered c_x (fp32)
  __shared__ __align__(16) u16 hbuf[2][128];    // bf16 h ping-pong: h_t -> hbuf[t&1]
  __shared__ __align__(16) float cbuf[2][128];  // fp32 c ping-pong: c_t -> cbuf[t&1]
  __shared__ float gca[512];                    // [0,384): wi_c ; [384,512): a_wi

  for (int i = tid; i < 16 * 136; i += 512) { Asg[i] = 0; Psg[i] = 0; }
  if (tid < 128) {
    hbuf[0][tid] = 0; hbuf[1][tid] = 0;
    cbuf[0][tid] = 0.0f; cbuf[1][tid] = 0.0f;
  }

  // persistent B-fragments (bf16) ------------------------------------------
  short8 wgwf[3][8];  // gate g in {f,i,g}: col = g*128 + h; kt 0..3 h-part, 4..7 sw-part
#pragma unroll
  for (int g = 0; g < 3; ++g) {
    const int n = g * 128 + h;
#pragma unroll
    for (int kt = 0; kt < 8; ++kt)
      wgwf[g][kt] = *(const short8*)(WgwT + (size_t)n * 256 + kt * 32 + qd * 8);
  }
  short8 wacf[4][4];  // j=0: a_hh col h ; j=1..3: w_hh_c gate cols (j-1)*128+h
#pragma unroll
  for (int j = 0; j < 4; ++j) {
    const int n = j * 128 + h;
#pragma unroll
    for (int kt = 0; kt < 4; ++kt)
      wacf[j][kt] = *(const short8*)(WahcT + (size_t)n * 128 + kt * 32 + qd * 8);
  }
  const float bw0 = bias_w[h], bw1 = bias_w[128 + h], bw2 = bias_w[256 + h];

  // sw A-fragments come straight from global in fragment layout: lane
  // (l16,qd) holds sw[l16&7][kt*32+qd*8 ..+7]. Rows 8..15 duplicate 0..7;
  // harmless -- MFMA output rows are independent and rows 8..15 discarded.
  const u16* swfbase = swb + (size_t)(l16 & 7) * CH + qd * 8;
  short8 swf[4];
#pragma unroll
  for (int kt = 0; kt < 4; ++kt)
    swf[kt] = *(const short8*)(swfbase + kt * 32);  // t = 0

  // pipeline preload for t=0 (src/cnt also for t=1) -------------------------
  int src_c = srcb[wv];
  int cnt_c = cntb[0];
  int src_n = srcb[CX + wv];
  int cnt_n = cntb[1];
  float2 h2c, c2c;
  h2c = *(const float2*)(hs + (size_t)src_c * CH + 2 * ln);   // poison at t=0, masked (cnt=0)
  c2c = *(const float2*)(cs + (size_t)src_c * CH + 2 * ln);
  float wicac = wicab[tid];
  float2 h2n = {0.f, 0.f}, c2n = {0.f, 0.f};
  float wican = 0.f;
  int src_n2 = 0, cnt_n2 = 0;
  __syncthreads();  // LDS init visible (full sync once; drains preloads too)

  for (int t = 0; t < CT; ++t) {
    const int par = t & 1;        // parity holding h_{t-2}; epilogue writes h_t here
    const int parp = par ^ 1;     // parity holding h_{t-1}

    // ---- stage 1: stage A-matrix rows (h_x, h0), c_x, wi parts -----------
    // src_c <= t-1. Rows t-1 and t-2 resolve from LDS ping-pong (so global
    // gathers only ever touch rows <= t-2, giving stores 2 barriers to land).
    if (src_c == t - 1) {
      *(u32*)&Asg[wv * 136 + 2 * ln] = *(const u32*)&hbuf[parp][2 * ln];
      *(float2*)&Csg[wv * 128 + 2 * ln] = *(const float2*)&cbuf[parp][2 * ln];
    } else if (src_c == t - 2) {
      *(u32*)&Asg[wv * 136 + 2 * ln] = *(const u32*)&hbuf[par][2 * ln];
      *(float2*)&Csg[wv * 128 + 2 * ln] = *(const float2*)&cbuf[par][2 * ln];
    } else {
      *(u32*)&Asg[wv * 136 + 2 * ln] = (u32)f2b(h2c.x) | ((u32)f2b(h2c.y) << 16);
      *(float2*)&Csg[wv * 128 + 2 * ln] = c2c;
    }
    gca[tid] = wicac;
    if (wv == 7)  // Asg row 8 = h0 (= h_{t-1}) -> gc comes from the same fragment
      *(u32*)&Asg[8 * 136 + 2 * ln] = *(const u32*)&hbuf[parp][2 * ln];
    barrier_lgkm();  // barrier A (LDS-only: nothing global crosses here)

    // ---- stage 2: prefetch for t+1 (in flight through barrier C) ---------
    // All loads unconditional (clamped) -> fixed vmem-op floor per iter for
    // the counted vmcnt at barrier C. Racy gathers (src_n in {t-1,t}) are
    // discarded at consumption (LDS-history path); the load is harmless.
    {
      const int tn = (t + 1 < CT) ? (t + 1) : t;
      const int tn2 = (t + 2 < CT) ? (t + 2) : (CT - 1);
      h2n = *(const float2*)(hs + (size_t)src_n * CH + 2 * ln);
      c2n = *(const float2*)(cs + (size_t)src_n * CH + 2 * ln);
      wican = wicab[(size_t)tn * 512 + tid];
      src_n2 = srcb[tn2 * CX + wv];
      cnt_n2 = cntb[tn2];
    }

    // ---- stage 3: gw = [h_x|sw] @ [w_hh_w;w_ih_w] + gc from same frag ----
    // One Asg fragment read feeds BOTH the gw h-part (d0..d2) and the gc
    // chains (e1..e3): row 8 = h0 -> e*[row 8] = gc. Rows 0..7 of e* and
    // rows 8..15 of d* are discarded (independent MFMA rows).
    f32x4 d0 = {0.f, 0.f, 0.f, 0.f}, d1 = d0, d2 = d0;
    f32x4 e1 = d0, e2 = d0, e3 = d0;
#pragma unroll
    for (int kt = 0; kt < 4; ++kt) {
      short8 a = *(const short8*)&Asg[l16 * 136 + kt * 32 + qd * 8];
      d0 = mfma16(a, wgwf[0][kt], d0);
      d1 = mfma16(a, wgwf[1][kt], d1);
      d2 = mfma16(a, wgwf[2][kt], d2);
      e1 = mfma16(a, wacf[1][kt], e1);
      e2 = mfma16(a, wacf[2][kt], e2);
      e3 = mfma16(a, wacf[3][kt], e3);
    }
    {
      const int tn = (t + 1 < CT) ? (t + 1) : t;
      const u16* swfn = swfbase + (size_t)tn * CX * CH;
#pragma unroll
      for (int kt = 0; kt < 4; ++kt) {
        d0 = mfma16(swf[kt], wgwf[0][4 + kt], d0);
        d1 = mfma16(swf[kt], wgwf[1][4 + kt], d1);
        d2 = mfma16(swf[kt], wgwf[2][4 + kt], d2);
        swf[kt] = *(const short8*)(swfn + kt * 32);  // reload for t+1 after last use
      }
    }
    // gc row (D row 8 = qd 2, reg 0) lives at lane 32+l16 of this wave
    const float gi_d = __shfl(e1[0], 32 + l16, 64);
    const float go_d = __shfl(e2[0], 32 + l16, 64);
    const float gg_d = __shfl(e3[0], 32 + l16, 64);
    const float awi = gca[384 + h];
    const float i_g = sigf(gi_d + gca[h]);
    const float o_g = sigf(go_d + gca[128 + h]);
    const float g_g = tanhfast(gg_d + gca[256 + h]);

    float c1s[4] = {0.f, 0.f, 0.f, 0.f};
    if (qd < 2) {  // rows 0..7 = real slots
#pragma unroll
      for (int r = 0; r < 4; ++r) {
        const int row = qd * 4 + r;
        const float cx = Csg[row * 128 + h];
        const float fg = sigf(d0[r] + bw0);
        const float ig = sigf(d1[r] + bw1);
        const float gg = tanhfast(d2[r] + bw2);
        const float v = fg * cx + ig * gg;
        c1s[r] = v;
        Psg[row * 136 + h] = f2b(v);
      }
    }
    barrier_lgkm();  // barrier B (LDS-only: prefetch loads stay in flight)

    // ---- stage 5: alpha = c1_skip @ a_hh, softmax-combine ----------------
    // Psg rows 8..15 stay zero (never written after init); their e0 rows
    // are always masked (cnt_c <= 8).
    f32x4 e0 = {0.f, 0.f, 0.f, 0.f};
#pragma unroll
    for (int kt = 0; kt < 4; ++kt) {
      short8 a = *(const short8*)&Psg[l16 * 136 + kt * 32 + qd * 8];
      e0 = mfma16(a, wacf[0][kt], e0);
    }
    float pe = 0.0f, pec = 0.0f;
#pragma unroll
    for (int r = 0; r < 4; ++r) {
      const int row = qd * 4 + r;
      if (row < cnt_c) {  // rows >= cnt masked (exp -> 0)
        const float al = sigf(e0[r] + awi);
        const float e = __expf(al);
        pe += e;
        pec += e * c1s[r];
      }
    }
    pe += __shfl_xor(pe, 16, 64);  pec += __shfl_xor(pec, 16, 64);
    pe += __shfl_xor(pe, 32, 64);  pec += __shfl_xor(pec, 32, 64);
    const float ei = __expf(i_g);
    const float c1 = __fdividef(ei * g_g + pec, ei + pe);
    const float h1 = o_g * tanhfast(c1);

    // ---- stage 6: epilogue ----------------------------------------------
    if (qd == 0) {
      hs[(size_t)t * CH + h] = h1;
      cs[(size_t)t * CH + h] = c1;
      hbuf[par][h] = f2b(h1);
      cbuf[par][h] = c1;
    }
    barrier_vm8();  // barrier C: counted vmcnt — iter t-1 stores L2-visible
                    // (next-iter global gathers touch rows <= t-1 only);
                    // own stores + swf/gather prefetches stay in flight.

    // rotate pipeline
    h2c = h2n; c2c = c2n; wicac = wican;
    src_c = src_n; cnt_c = cnt_n; src_n = src_n2; cnt_n = cnt_n2;
  }
}

extern "C" void kernel_launch(void* const* d_in, const int* in_sizes, int n_in,
                              void* d_out, int out_size, void* d_ws, size_t ws_size,
                              hipStream_t stream) {
  (void)in_sizes; (void)n_in; (void)out_size; (void)ws_size;
  const float* inp    = (const float*)d_in[0];
  const float* skw    = (const float*)d_in[1];
  const int*   ssrc   = (const int*)d_in[3];
  const int*   scnt   = (const int*)d_in[4];
  const float* w_ih_c = (const float*)d_in[5];
  const float* w_hh_c = (const float*)d_in[6];
  const float* bias_c = (const float*)d_in[7];
  const float* a_ih   = (const float*)d_in[8];
  const float* a_hh   = (const float*)d_in[9];
  const float* a_bias = (const float*)d_in[10];
  const float* w_ih_w = (const float*)d_in[11];
  const float* w_hh_w = (const float*)d_in[12];
  const float* bias_w = (const float*)d_in[13];

  char* ws = (char*)d_ws;
  u16*   WgwT  = (u16*)(ws);
  u16*   WahcT = (u16*)(ws + 196608);
  u16*   WcaT  = (u16*)(ws + 327680);
  float* wica  = (float*)(ws + 458752);
  u16*   swb16 = (u16*)(ws + 458752 + 67108864);
  float* out   = (float*)d_out;

  prep_kernel<<<224, 1024, 0, stream>>>(w_ih_c, w_hh_c, a_ih, a_hh, w_ih_w, w_hh_w,
                                        WgwT, WahcT, WcaT);
  prep_sw_kernel<<<4096, 1024, 0, stream>>>(skw, swb16);
  proj_kernel<<<512, 256, 0, stream>>>(inp, WcaT, bias_c, a_bias, wica);
  scan_kernel<<<64, 512, 0, stream>>>(swb16, ssrc, scnt, bias_w, WgwT, WahcT, wica, out);
}